// Round 4
// baseline (501.728 us; speedup 1.0000x reference)
//
#include <hip/hip_runtime.h>
#include <math.h>

// MeanShift R12: QK^T on MFMA (map-agnostic, correct), PV on VALU (reads the
// HW-verified C/D layout directly -- no dependence on the undocumented A/B
// fragment k-map that sank R9-R11).
//   u(n,m) = 2p'.y' - |p'|^2 - |y'|^2   (scaled space, s^2 = 50*log2e)
//   w = exp2(u);  num/den = w @ [p',1]
// QK^T: one v_mfma_f32_32x32x16_bf16 per 32x32 tile. P/Y features packed
// POSITIONALLY (slot q of P pairs with slot q of Y regardless of the HW's
// position->k bijection, since A and B use the same map). hi/lo bf16 split
// makes products exact in f32; -|y'|^2 enters via the f32 C operand.
// PV: per lane, 16 u-values at rows m0+crow(r,h), crow=(r&3)+8(r>>2)+4h
// (HW-verified m74/m101). w=exp2(u) then 2x v_pk_fma_f32 against broadcast
// float4 (p'x,p'y,p'z,1). Halves combined via __shfl, atomicAdd exchange.

#define NPTS 9216
#define NB 2
#define TOT (NB * NPTS)
#define NTIL 288              // 32-wide n tiles per batch
#define TPW 18                // m-tiles per wave (16 waves per n-tile)
#define LOG2E 1.44269504088896340736f

typedef float v2f __attribute__((ext_vector_type(2)));
typedef short bf16x8 __attribute__((ext_vector_type(8)));
typedef float f32x16 __attribute__((ext_vector_type(16)));

__device__ __forceinline__ unsigned short bf16r(float x) {
    unsigned u = __float_as_uint(x);
    return (unsigned short)((u + 0x7fffu + ((u >> 16) & 1u)) >> 16);
}
__device__ __forceinline__ float bf16f(unsigned short h) {
    return __uint_as_float((unsigned)h << 16);
}

// Pfeat[b][m][16] bf16 slots (positional): [Ahx,Ahy,Ahz, Ahx,Ahy,Ahz,
//   Alx,Aly, Alz,Alx,Aly,Alz, Nh,Nl, 0,0],  A=2p', N=-|p'|^2
// Yfeat positional twin: [Yh0,Yh1,Yh2, Yl0,Yl1,Yl2, Yh0,Yh1,
//   Yh2,Yl0,Yl1,Yl2, 1,1, 0,0]
// pts4[b][m] = (p'x, p'y, p'z, 1.0)  (V for the VALU PV step)
__global__ __launch_bounds__(256) void ms_feat(const float* __restrict__ x,
                                               short* __restrict__ pfeat,
                                               float4* __restrict__ pts4,
                                               float s) {
    int gid = blockIdx.x * 256 + threadIdx.x;       // 0..18431
    int b = gid / NPTS, m = gid - b * NPTS;
    const float* xb = x + b * 3 * NPTS;
    float p0 = xb[m] * s, p1 = xb[NPTS + m] * s, p2 = xb[2 * NPTS + m] * s;
    float np = -fmaf(p0, p0, fmaf(p1, p1, p2 * p2));
    float a0 = 2.f * p0, a1 = 2.f * p1, a2 = 2.f * p2;
    unsigned short Ah0 = bf16r(a0), Ah1 = bf16r(a1), Ah2 = bf16r(a2);
    unsigned short Al0 = bf16r(a0 - bf16f(Ah0));
    unsigned short Al1 = bf16r(a1 - bf16f(Ah1));
    unsigned short Al2 = bf16r(a2 - bf16f(Ah2));
    unsigned short Nh = bf16r(np);
    unsigned short Nl = bf16r(np - bf16f(Nh));
    uint4* dst = (uint4*)(pfeat + (size_t)gid * 16);
    dst[0] = make_uint4((unsigned)Ah0 | ((unsigned)Ah1 << 16),
                        (unsigned)Ah2 | ((unsigned)Ah0 << 16),
                        (unsigned)Ah1 | ((unsigned)Ah2 << 16),
                        (unsigned)Al0 | ((unsigned)Al1 << 16));
    dst[1] = make_uint4((unsigned)Al2 | ((unsigned)Al0 << 16),
                        (unsigned)Al1 | ((unsigned)Al2 << 16),
                        (unsigned)Nh  | ((unsigned)Nl  << 16), 0u);
    pts4[gid] = make_float4(p0, p1, p2, 1.0f);
}

__global__ __launch_bounds__(256, 4) void ms_iter(
    const float* __restrict__ x, const float4* __restrict__ accIn,
    float4* __restrict__ accOut, const short* __restrict__ pfeat,
    const float4* __restrict__ pts4, float s, int first) {

    const int tid = threadIdx.x;
    const int l   = tid & 63;
    const int wv  = tid >> 6;
    const int col = l & 31;                 // n within tile
    const int hi  = l >> 5;

    int bid = blockIdx.x;
    const int b  = bid / (4 * NTIL);
    int r        = bid - b * 4 * NTIL;
    const int nt = r >> 2;
    const int mc = r & 3;
    const int n  = nt * 32 + col;
    const int t0 = (mc * 4 + wv) * TPW;

    // ---- y' for this lane's n (scaled), split to bf16 hi/lo ----
    float y0, y1, y2;
    if (first) {
        const float* xb = x + b * 3 * NPTS;
        y0 = xb[n] * s; y1 = xb[NPTS + n] * s; y2 = xb[2 * NPTS + n] * s;
    } else {
        float4 a = accIn[b * NPTS + n];
        float inv = 1.0f / a.w;
        y0 = a.x * inv; y1 = a.y * inv; y2 = a.z * inv;
    }
    float ny = -fmaf(y0, y0, fmaf(y1, y1, y2 * y2));   // exact f32, via C
    unsigned short Yh0 = bf16r(y0), Yh1 = bf16r(y1), Yh2 = bf16r(y2);
    unsigned short Yl0 = bf16r(y0 - bf16f(Yh0));
    unsigned short Yl1 = bf16r(y1 - bf16f(Yh1));
    unsigned short Yl2 = bf16r(y2 - bf16f(Yh2));
    union { unsigned w[4]; bf16x8 v; } yf;
    if (hi == 0) {
        yf.w[0] = (unsigned)Yh0 | ((unsigned)Yh1 << 16);
        yf.w[1] = (unsigned)Yh2 | ((unsigned)Yl0 << 16);
        yf.w[2] = (unsigned)Yl1 | ((unsigned)Yl2 << 16);
        yf.w[3] = (unsigned)Yh0 | ((unsigned)Yh1 << 16);
    } else {
        yf.w[0] = (unsigned)Yh2 | ((unsigned)Yl0 << 16);
        yf.w[1] = (unsigned)Yl1 | ((unsigned)Yl2 << 16);
        yf.w[2] = 0x3F803F80u;                          // (1.0, 1.0)
        yf.w[3] = 0u;
    }

    f32x16 cin;
#pragma unroll
    for (int i = 0; i < 16; ++i) cin[i] = ny;

    v2f Axy = (v2f){0.f, 0.f};              // (num_x, num_y)
    v2f Azw = (v2f){0.f, 0.f};              // (num_z, den)

    const short*  pfb = pfeat + (size_t)b * NPTS * 16;
    const float4* pbb = pts4 + (size_t)b * NPTS + 4 * hi;

#pragma unroll 2
    for (int t = t0; t < t0 + TPW; ++t) {
        const int m0 = t * 32;
        bf16x8 pf = *(const bf16x8*)(pfb + (size_t)(m0 + col) * 16 + 8 * hi);
        f32x16 u = __builtin_amdgcn_mfma_f32_32x32x16_bf16(pf, yf.v, cin,
                                                           0, 0, 0);
        // u[r] = score[m0 + (r&3) + 8*(r>>2) + 4*hi][n]  (HW-verified C/D)
        const float4* pb = pbb + m0;        // m = m0 + 4*hi + (r&3) + 8*(r>>2)
#pragma unroll
        for (int q = 0; q < 4; ++q) {
            float4 P0 = pb[8 * q + 0];
            float4 P1 = pb[8 * q + 1];
            float4 P2 = pb[8 * q + 2];
            float4 P3 = pb[8 * q + 3];
            float w0 = __builtin_amdgcn_exp2f(u[4 * q + 0]);
            float w1 = __builtin_amdgcn_exp2f(u[4 * q + 1]);
            float w2 = __builtin_amdgcn_exp2f(u[4 * q + 2]);
            float w3 = __builtin_amdgcn_exp2f(u[4 * q + 3]);
            Axy = __builtin_elementwise_fma((v2f){w0, w0},
                                            (v2f){P0.x, P0.y}, Axy);
            Azw = __builtin_elementwise_fma((v2f){w0, w0},
                                            (v2f){P0.z, P0.w}, Azw);
            Axy = __builtin_elementwise_fma((v2f){w1, w1},
                                            (v2f){P1.x, P1.y}, Axy);
            Azw = __builtin_elementwise_fma((v2f){w1, w1},
                                            (v2f){P1.z, P1.w}, Azw);
            Axy = __builtin_elementwise_fma((v2f){w2, w2},
                                            (v2f){P2.x, P2.y}, Axy);
            Azw = __builtin_elementwise_fma((v2f){w2, w2},
                                            (v2f){P2.z, P2.w}, Azw);
            Axy = __builtin_elementwise_fma((v2f){w3, w3},
                                            (v2f){P3.x, P3.y}, Axy);
            Azw = __builtin_elementwise_fma((v2f){w3, w3},
                                            (v2f){P3.z, P3.w}, Azw);
        }
    }

    // halves hold disjoint m-sets for the same n: combine h1 into h0.
    float hx = __shfl(Axy[0], col + 32);
    float hy = __shfl(Axy[1], col + 32);
    float hz = __shfl(Azw[0], col + 32);
    float hd = __shfl(Azw[1], col + 32);
    if (l < 32) {
        float* dst = (float*)&accOut[b * NPTS + n];
        atomicAdd(dst + 0, Axy[0] + hx);
        atomicAdd(dst + 1, Axy[1] + hy);
        atomicAdd(dst + 2, Azw[0] + hz);
        atomicAdd(dst + 3, Azw[1] + hd);
    }
}

__global__ __launch_bounds__(256) void ms_pack(const float4* __restrict__ acc4,
                                               float* __restrict__ out,
                                               float invs) {
    int gid = blockIdx.x * 256 + threadIdx.x;
    int b = gid / NPTS;
    int n = gid - b * NPTS;
    float4 a = acc4[gid];
    float f = invs / a.w;                   // unscale + normalize
    float* ob = out + b * 3 * NPTS;
    ob[n]            = a.x * f;
    ob[NPTS + n]     = a.y * f;
    ob[2 * NPTS + n] = a.z * f;
}

extern "C" void kernel_launch(void* const* d_in, const int* in_sizes, int n_in,
                              void* d_out, int out_size, void* d_ws, size_t ws_size,
                              hipStream_t stream) {
    const float* x = (const float*)d_in[0];
    float* out = (float*)d_out;
    float s = sqrtf(50.0f * LOG2E);

    float4* acc   = (float4*)d_ws;                      // 5*TOT*16B = 1.47MB
    short*  pfeat = (short*)(acc + (size_t)5 * TOT);    // TOT*16*2B = 590KB
    float4* pts4  = (float4*)(pfeat + (size_t)TOT * 16);// TOT*16B = 295KB

    hipMemsetAsync(acc, 0, (size_t)5 * TOT * sizeof(float4), stream);
    ms_feat<<<TOT / 256, 256, 0, stream>>>(x, pfeat, pts4, s);

    for (int it = 0; it < 5; ++it) {
        const float4* accIn = (it == 0) ? nullptr : acc + (size_t)(it - 1) * TOT;
        ms_iter<<<NB * NTIL * 4, 256, 0, stream>>>(
            x, accIn, acc + (size_t)it * TOT, pfeat, pts4, s, it == 0 ? 1 : 0);
    }
    ms_pack<<<TOT / 256, 256, 0, stream>>>(acc + (size_t)4 * TOT, out, 1.0f / s);
}

// Round 5
// 372.122 us; speedup vs baseline: 1.3483x; 1.3483x over previous
//
#include <hip/hip_runtime.h>
#include <math.h>

// MeanShift R13: R12 structure (QK^T on MFMA map-agnostic + PV on VALU using
// the HW-verified C/D layout) with the PV data path fixed:
//  - R12 was latency-bound (VALUBusy 17%, VGPR 40): 16 broadcast global
//    loads/tile serialized at ~200cyc each.
//  - R13 stages the block's 2304-point m-range (36KB float4) in LDS once,
//    then each tile's 16 P-values are hoisted ds_read_b128 broadcasts
//    (uniform per half-wave -> conflict-free), all in flight at once.
//  - launch_bounds(256,4) -> 128 VGPR budget so P[16] stays live.
//  - two accumulator chains (even/odd q) for FMA ILP.
//   u(n,m) = 2p'.y' - |p'|^2 - |y'|^2   (scaled space, s^2 = 50*log2e)
//   w = exp2(u);  num/den = w @ [p',1]

#define NPTS 9216
#define NB 2
#define TOT (NB * NPTS)
#define NTIL 288              // 32-wide n tiles per batch
#define TPW 18                // m-tiles per wave (4 waves -> 72 tiles/block)
#define MBLK 2304             // m-points per block (= 72 tiles * 32)
#define LOG2E 1.44269504088896340736f

typedef float v2f __attribute__((ext_vector_type(2)));
typedef short bf16x8 __attribute__((ext_vector_type(8)));
typedef float f32x16 __attribute__((ext_vector_type(16)));

__device__ __forceinline__ unsigned short bf16r(float x) {
    unsigned u = __float_as_uint(x);
    return (unsigned short)((u + 0x7fffu + ((u >> 16) & 1u)) >> 16);
}
__device__ __forceinline__ float bf16f(unsigned short h) {
    return __uint_as_float((unsigned)h << 16);
}

// Pfeat[b][m][16] bf16 slots (positional): [Ahx,Ahy,Ahz, Ahx,Ahy,Ahz,
//   Alx,Aly, Alz,Alx,Aly,Alz, Nh,Nl, 0,0],  A=2p', N=-|p'|^2
// Yfeat positional twin: [Yh0,Yh1,Yh2, Yl0,Yl1,Yl2, Yh0,Yh1,
//   Yh2,Yl0,Yl1,Yl2, 1,1, 0,0]
// pts4[b][m] = (p'x, p'y, p'z, 1.0)  (V for the VALU PV step)
__global__ __launch_bounds__(256) void ms_feat(const float* __restrict__ x,
                                               short* __restrict__ pfeat,
                                               float4* __restrict__ pts4,
                                               float s) {
    int gid = blockIdx.x * 256 + threadIdx.x;       // 0..18431
    int b = gid / NPTS, m = gid - b * NPTS;
    const float* xb = x + b * 3 * NPTS;
    float p0 = xb[m] * s, p1 = xb[NPTS + m] * s, p2 = xb[2 * NPTS + m] * s;
    float np = -fmaf(p0, p0, fmaf(p1, p1, p2 * p2));
    float a0 = 2.f * p0, a1 = 2.f * p1, a2 = 2.f * p2;
    unsigned short Ah0 = bf16r(a0), Ah1 = bf16r(a1), Ah2 = bf16r(a2);
    unsigned short Al0 = bf16r(a0 - bf16f(Ah0));
    unsigned short Al1 = bf16r(a1 - bf16f(Ah1));
    unsigned short Al2 = bf16r(a2 - bf16f(Ah2));
    unsigned short Nh = bf16r(np);
    unsigned short Nl = bf16r(np - bf16f(Nh));
    uint4* dst = (uint4*)(pfeat + (size_t)gid * 16);
    dst[0] = make_uint4((unsigned)Ah0 | ((unsigned)Ah1 << 16),
                        (unsigned)Ah2 | ((unsigned)Ah0 << 16),
                        (unsigned)Ah1 | ((unsigned)Ah2 << 16),
                        (unsigned)Al0 | ((unsigned)Al1 << 16));
    dst[1] = make_uint4((unsigned)Al2 | ((unsigned)Al0 << 16),
                        (unsigned)Al1 | ((unsigned)Al2 << 16),
                        (unsigned)Nh  | ((unsigned)Nl  << 16), 0u);
    pts4[gid] = make_float4(p0, p1, p2, 1.0f);
}

__global__ __launch_bounds__(256, 4) void ms_iter(
    const float* __restrict__ x, const float4* __restrict__ accIn,
    float4* __restrict__ accOut, const short* __restrict__ pfeat,
    const float4* __restrict__ pts4, float s, int first) {

    __shared__ float4 lds4[MBLK];           // 36 KB: this block's P range

    const int tid = threadIdx.x;
    const int l   = tid & 63;
    const int wv  = tid >> 6;
    const int col = l & 31;                 // n within tile
    const int hi  = l >> 5;

    int bid = blockIdx.x;
    const int b  = bid / (4 * NTIL);
    int r        = bid - b * 4 * NTIL;
    const int nt = r >> 2;
    const int mc = r & 3;
    const int n  = nt * 32 + col;
    const int mbase = mc * MBLK;            // block's m range start

    // ---- stage this block's 2304 P float4s into LDS (coalesced) ----
    {
        const float4* src = pts4 + (size_t)b * NPTS + mbase;
        for (int i = tid; i < MBLK; i += 256) lds4[i] = src[i];
    }

    // ---- y' for this lane's n (scaled), split to bf16 hi/lo ----
    float y0, y1, y2;
    if (first) {
        const float* xb = x + b * 3 * NPTS;
        y0 = xb[n] * s; y1 = xb[NPTS + n] * s; y2 = xb[2 * NPTS + n] * s;
    } else {
        float4 a = accIn[b * NPTS + n];
        float inv = 1.0f / a.w;
        y0 = a.x * inv; y1 = a.y * inv; y2 = a.z * inv;
    }
    float ny = -fmaf(y0, y0, fmaf(y1, y1, y2 * y2));   // exact f32, via C
    unsigned short Yh0 = bf16r(y0), Yh1 = bf16r(y1), Yh2 = bf16r(y2);
    unsigned short Yl0 = bf16r(y0 - bf16f(Yh0));
    unsigned short Yl1 = bf16r(y1 - bf16f(Yh1));
    unsigned short Yl2 = bf16r(y2 - bf16f(Yh2));
    union { unsigned w[4]; bf16x8 v; } yf;
    if (hi == 0) {
        yf.w[0] = (unsigned)Yh0 | ((unsigned)Yh1 << 16);
        yf.w[1] = (unsigned)Yh2 | ((unsigned)Yl0 << 16);
        yf.w[2] = (unsigned)Yl1 | ((unsigned)Yl2 << 16);
        yf.w[3] = (unsigned)Yh0 | ((unsigned)Yh1 << 16);
    } else {
        yf.w[0] = (unsigned)Yh2 | ((unsigned)Yl0 << 16);
        yf.w[1] = (unsigned)Yl1 | ((unsigned)Yl2 << 16);
        yf.w[2] = 0x3F803F80u;                          // (1.0, 1.0)
        yf.w[3] = 0u;
    }

    f32x16 cin;
#pragma unroll
    for (int i = 0; i < 16; ++i) cin[i] = ny;

    v2f Axy0 = (v2f){0.f, 0.f}, Azw0 = (v2f){0.f, 0.f};
    v2f Axy1 = (v2f){0.f, 0.f}, Azw1 = (v2f){0.f, 0.f};

    const short* pfb = pfeat + (size_t)b * NPTS * 16;

    __syncthreads();

#pragma unroll 2
    for (int tt = 0; tt < TPW; ++tt) {
        const int tL  = wv * TPW + tt;      // local tile in block
        const int m0L = tL * 32;            // local m start
        const int m0  = mbase + m0L;        // global m start
        bf16x8 pf = *(const bf16x8*)(pfb + (size_t)(m0 + col) * 16 + 8 * hi);

        // hoist all 16 P broadcasts (independent of MFMA result)
        const float4* pb = lds4 + m0L + 4 * hi;
        float4 P[16];
#pragma unroll
        for (int q = 0; q < 4; ++q) {
            P[4 * q + 0] = pb[8 * q + 0];
            P[4 * q + 1] = pb[8 * q + 1];
            P[4 * q + 2] = pb[8 * q + 2];
            P[4 * q + 3] = pb[8 * q + 3];
        }

        f32x16 u = __builtin_amdgcn_mfma_f32_32x32x16_bf16(pf, yf.v, cin,
                                                           0, 0, 0);
        // u[r] = score[m0 + (r&3) + 8*(r>>2) + 4*hi][n]  (HW-verified C/D)
#pragma unroll
        for (int q = 0; q < 4; ++q) {
            float w0 = __builtin_amdgcn_exp2f(u[4 * q + 0]);
            float w1 = __builtin_amdgcn_exp2f(u[4 * q + 1]);
            float w2 = __builtin_amdgcn_exp2f(u[4 * q + 2]);
            float w3 = __builtin_amdgcn_exp2f(u[4 * q + 3]);
            float4 P0 = P[4 * q + 0], P1 = P[4 * q + 1];
            float4 P2 = P[4 * q + 2], P3 = P[4 * q + 3];
            if (q & 1) {
                Axy1 = __builtin_elementwise_fma((v2f){w0, w0}, (v2f){P0.x, P0.y}, Axy1);
                Azw1 = __builtin_elementwise_fma((v2f){w0, w0}, (v2f){P0.z, P0.w}, Azw1);
                Axy1 = __builtin_elementwise_fma((v2f){w1, w1}, (v2f){P1.x, P1.y}, Axy1);
                Azw1 = __builtin_elementwise_fma((v2f){w1, w1}, (v2f){P1.z, P1.w}, Azw1);
                Axy1 = __builtin_elementwise_fma((v2f){w2, w2}, (v2f){P2.x, P2.y}, Axy1);
                Azw1 = __builtin_elementwise_fma((v2f){w2, w2}, (v2f){P2.z, P2.w}, Azw1);
                Axy1 = __builtin_elementwise_fma((v2f){w3, w3}, (v2f){P3.x, P3.y}, Axy1);
                Azw1 = __builtin_elementwise_fma((v2f){w3, w3}, (v2f){P3.z, P3.w}, Azw1);
            } else {
                Axy0 = __builtin_elementwise_fma((v2f){w0, w0}, (v2f){P0.x, P0.y}, Axy0);
                Azw0 = __builtin_elementwise_fma((v2f){w0, w0}, (v2f){P0.z, P0.w}, Azw0);
                Axy0 = __builtin_elementwise_fma((v2f){w1, w1}, (v2f){P1.x, P1.y}, Axy0);
                Azw0 = __builtin_elementwise_fma((v2f){w1, w1}, (v2f){P1.z, P1.w}, Azw0);
                Axy0 = __builtin_elementwise_fma((v2f){w2, w2}, (v2f){P2.x, P2.y}, Axy0);
                Azw0 = __builtin_elementwise_fma((v2f){w2, w2}, (v2f){P2.z, P2.w}, Azw0);
                Axy0 = __builtin_elementwise_fma((v2f){w3, w3}, (v2f){P3.x, P3.y}, Axy0);
                Azw0 = __builtin_elementwise_fma((v2f){w3, w3}, (v2f){P3.z, P3.w}, Azw0);
            }
        }
    }

    v2f Axy = Axy0 + Axy1;
    v2f Azw = Azw0 + Azw1;

    // halves hold disjoint m-sets for the same n: combine h1 into h0.
    float hx = __shfl(Axy[0], col + 32);
    float hy = __shfl(Axy[1], col + 32);
    float hz = __shfl(Azw[0], col + 32);
    float hd = __shfl(Azw[1], col + 32);
    if (l < 32) {
        float* dst = (float*)&accOut[b * NPTS + n];
        atomicAdd(dst + 0, Axy[0] + hx);
        atomicAdd(dst + 1, Axy[1] + hy);
        atomicAdd(dst + 2, Azw[0] + hz);
        atomicAdd(dst + 3, Azw[1] + hd);
    }
}

__global__ __launch_bounds__(256) void ms_pack(const float4* __restrict__ acc4,
                                               float* __restrict__ out,
                                               float invs) {
    int gid = blockIdx.x * 256 + threadIdx.x;
    int b = gid / NPTS;
    int n = gid - b * NPTS;
    float4 a = acc4[gid];
    float f = invs / a.w;                   // unscale + normalize
    float* ob = out + b * 3 * NPTS;
    ob[n]            = a.x * f;
    ob[NPTS + n]     = a.y * f;
    ob[2 * NPTS + n] = a.z * f;
}

extern "C" void kernel_launch(void* const* d_in, const int* in_sizes, int n_in,
                              void* d_out, int out_size, void* d_ws, size_t ws_size,
                              hipStream_t stream) {
    const float* x = (const float*)d_in[0];
    float* out = (float*)d_out;
    float s = sqrtf(50.0f * LOG2E);

    float4* acc   = (float4*)d_ws;                      // 5*TOT*16B = 1.47MB
    short*  pfeat = (short*)(acc + (size_t)5 * TOT);    // TOT*16*2B = 590KB
    float4* pts4  = (float4*)(pfeat + (size_t)TOT * 16);// TOT*16B = 295KB

    hipMemsetAsync(acc, 0, (size_t)5 * TOT * sizeof(float4), stream);
    ms_feat<<<TOT / 256, 256, 0, stream>>>(x, pfeat, pts4, s);

    for (int it = 0; it < 5; ++it) {
        const float4* accIn = (it == 0) ? nullptr : acc + (size_t)(it - 1) * TOT;
        ms_iter<<<NB * NTIL * 4, 256, 0, stream>>>(
            x, accIn, acc + (size_t)it * TOT, pfeat, pts4, s, it == 0 ? 1 : 0);
    }
    ms_pack<<<TOT / 256, 256, 0, stream>>>(acc + (size_t)4 * TOT, out, 1.0f / s);
}

// Round 6
// 277.315 us; speedup vs baseline: 1.8092x; 1.3419x over previous
//
#include <hip/hip_runtime.h>
#include <math.h>

// MeanShift R14: R13 + (a) explicit register prefetch of the per-tile pfeat
// global load (R13 was latency-bound on it: VALUBusy 27%, VGPR 64 showed the
// compiler serialized load->mfma->exp), (b) occupancy bump: MBLK 2304->1536
// (LDS 36->24KB, 6 blocks/CU by LDS; grid 2304->3456 softens the tail).
// Structure unchanged: QK^T on MFMA (map-agnostic positional packing, exact
// via bf16 hi/lo split, -|y|^2 through f32 C), PV on VALU reading the
// HW-verified C/D layout (row=(r&3)+8(r>>2)+4h, col=l&31).
//   u(n,m) = 2p'.y' - |p'|^2 - |y'|^2   (scaled space, s^2 = 50*log2e)
//   w = exp2(u);  num/den = w @ [p',1]

#define NPTS 9216
#define NB 2
#define TOT (NB * NPTS)
#define NTIL 288              // 32-wide n tiles per batch
#define MSPL 6                // m-chunks per batch
#define MBLK 1536             // m-points per block (= 48 tiles * 32)
#define TPW 12                // m-tiles per wave (4 waves/block)
#define LOG2E 1.44269504088896340736f

typedef float v2f __attribute__((ext_vector_type(2)));
typedef short bf16x8 __attribute__((ext_vector_type(8)));
typedef float f32x16 __attribute__((ext_vector_type(16)));

__device__ __forceinline__ unsigned short bf16r(float x) {
    unsigned u = __float_as_uint(x);
    return (unsigned short)((u + 0x7fffu + ((u >> 16) & 1u)) >> 16);
}
__device__ __forceinline__ float bf16f(unsigned short h) {
    return __uint_as_float((unsigned)h << 16);
}

// Pfeat[b][m][16] bf16 slots (positional): [Ahx,Ahy,Ahz, Ahx,Ahy,Ahz,
//   Alx,Aly, Alz,Alx,Aly,Alz, Nh,Nl, 0,0],  A=2p', N=-|p'|^2
// Yfeat positional twin: [Yh0,Yh1,Yh2, Yl0,Yl1,Yl2, Yh0,Yh1,
//   Yh2,Yl0,Yl1,Yl2, 1,1, 0,0]
// pts4[b][m] = (p'x, p'y, p'z, 1.0)  (V for the VALU PV step)
__global__ __launch_bounds__(256) void ms_feat(const float* __restrict__ x,
                                               short* __restrict__ pfeat,
                                               float4* __restrict__ pts4,
                                               float s) {
    int gid = blockIdx.x * 256 + threadIdx.x;       // 0..18431
    int b = gid / NPTS, m = gid - b * NPTS;
    const float* xb = x + b * 3 * NPTS;
    float p0 = xb[m] * s, p1 = xb[NPTS + m] * s, p2 = xb[2 * NPTS + m] * s;
    float np = -fmaf(p0, p0, fmaf(p1, p1, p2 * p2));
    float a0 = 2.f * p0, a1 = 2.f * p1, a2 = 2.f * p2;
    unsigned short Ah0 = bf16r(a0), Ah1 = bf16r(a1), Ah2 = bf16r(a2);
    unsigned short Al0 = bf16r(a0 - bf16f(Ah0));
    unsigned short Al1 = bf16r(a1 - bf16f(Ah1));
    unsigned short Al2 = bf16r(a2 - bf16f(Ah2));
    unsigned short Nh = bf16r(np);
    unsigned short Nl = bf16r(np - bf16f(Nh));
    uint4* dst = (uint4*)(pfeat + (size_t)gid * 16);
    dst[0] = make_uint4((unsigned)Ah0 | ((unsigned)Ah1 << 16),
                        (unsigned)Ah2 | ((unsigned)Ah0 << 16),
                        (unsigned)Ah1 | ((unsigned)Ah2 << 16),
                        (unsigned)Al0 | ((unsigned)Al1 << 16));
    dst[1] = make_uint4((unsigned)Al2 | ((unsigned)Al0 << 16),
                        (unsigned)Al1 | ((unsigned)Al2 << 16),
                        (unsigned)Nh  | ((unsigned)Nl  << 16), 0u);
    pts4[gid] = make_float4(p0, p1, p2, 1.0f);
}

__global__ __launch_bounds__(256, 4) void ms_iter(
    const float* __restrict__ x, const float4* __restrict__ accIn,
    float4* __restrict__ accOut, const short* __restrict__ pfeat,
    const float4* __restrict__ pts4, float s, int first) {

    __shared__ float4 lds4[MBLK];           // 24 KB: this block's P range

    const int tid = threadIdx.x;
    const int l   = tid & 63;
    const int wv  = tid >> 6;
    const int col = l & 31;                 // n within tile
    const int hi  = l >> 5;

    int bid = blockIdx.x;
    const int b  = bid / (MSPL * NTIL);
    int r        = bid - b * (MSPL * NTIL);
    const int nt = r / MSPL;
    const int mc = r - nt * MSPL;
    const int n  = nt * 32 + col;
    const int mbase = mc * MBLK;            // block's m range start

    // ---- stage this block's 1536 P float4s into LDS (coalesced) ----
    {
        const float4* src = pts4 + (size_t)b * NPTS + mbase;
        for (int i = tid; i < MBLK; i += 256) lds4[i] = src[i];
    }

    // ---- y' for this lane's n (scaled), split to bf16 hi/lo ----
    float y0, y1, y2;
    if (first) {
        const float* xb = x + b * 3 * NPTS;
        y0 = xb[n] * s; y1 = xb[NPTS + n] * s; y2 = xb[2 * NPTS + n] * s;
    } else {
        float4 a = accIn[b * NPTS + n];
        float inv = 1.0f / a.w;
        y0 = a.x * inv; y1 = a.y * inv; y2 = a.z * inv;
    }
    float ny = -fmaf(y0, y0, fmaf(y1, y1, y2 * y2));   // exact f32, via C
    unsigned short Yh0 = bf16r(y0), Yh1 = bf16r(y1), Yh2 = bf16r(y2);
    unsigned short Yl0 = bf16r(y0 - bf16f(Yh0));
    unsigned short Yl1 = bf16r(y1 - bf16f(Yh1));
    unsigned short Yl2 = bf16r(y2 - bf16f(Yh2));
    union { unsigned w[4]; bf16x8 v; } yf;
    if (hi == 0) {
        yf.w[0] = (unsigned)Yh0 | ((unsigned)Yh1 << 16);
        yf.w[1] = (unsigned)Yh2 | ((unsigned)Yl0 << 16);
        yf.w[2] = (unsigned)Yl1 | ((unsigned)Yl2 << 16);
        yf.w[3] = (unsigned)Yh0 | ((unsigned)Yh1 << 16);
    } else {
        yf.w[0] = (unsigned)Yh2 | ((unsigned)Yl0 << 16);
        yf.w[1] = (unsigned)Yl1 | ((unsigned)Yl2 << 16);
        yf.w[2] = 0x3F803F80u;                          // (1.0, 1.0)
        yf.w[3] = 0u;
    }

    f32x16 cin;
#pragma unroll
    for (int i = 0; i < 16; ++i) cin[i] = ny;

    v2f Axy0 = (v2f){0.f, 0.f}, Azw0 = (v2f){0.f, 0.f};
    v2f Axy1 = (v2f){0.f, 0.f}, Azw1 = (v2f){0.f, 0.f};

    // per-lane pfeat base for this wave's first tile; advances 512 shorts/tile
    const short* pfl = pfeat + (size_t)b * NPTS * 16 +
                       (size_t)(mbase + wv * TPW * 32 + col) * 16 + 8 * hi;

    __syncthreads();

    // prefetch tile 0's A-fragment
    bf16x8 pf_n = *(const bf16x8*)pfl;

#pragma unroll 2
    for (int tt = 0; tt < TPW; ++tt) {
        bf16x8 pf = pf_n;
        // prefetch next tile's fragment (dead on last iter; overread lands in
        // the adjacent pts4 workspace buffer -- mapped, unused)
        pf_n = *(const bf16x8*)(pfl + (size_t)(tt + 1) * 512);

        const int m0L = (wv * TPW + tt) * 32;   // local m start
        // hoist all 16 P broadcasts (independent of MFMA result)
        const float4* pb = lds4 + m0L + 4 * hi;
        float4 P[16];
#pragma unroll
        for (int q = 0; q < 4; ++q) {
            P[4 * q + 0] = pb[8 * q + 0];
            P[4 * q + 1] = pb[8 * q + 1];
            P[4 * q + 2] = pb[8 * q + 2];
            P[4 * q + 3] = pb[8 * q + 3];
        }

        f32x16 u = __builtin_amdgcn_mfma_f32_32x32x16_bf16(pf, yf.v, cin,
                                                           0, 0, 0);
        // u[r] = score[m0 + (r&3) + 8*(r>>2) + 4*hi][n]  (HW-verified C/D)
#pragma unroll
        for (int q = 0; q < 4; ++q) {
            float w0 = __builtin_amdgcn_exp2f(u[4 * q + 0]);
            float w1 = __builtin_amdgcn_exp2f(u[4 * q + 1]);
            float w2 = __builtin_amdgcn_exp2f(u[4 * q + 2]);
            float w3 = __builtin_amdgcn_exp2f(u[4 * q + 3]);
            float4 P0 = P[4 * q + 0], P1 = P[4 * q + 1];
            float4 P2 = P[4 * q + 2], P3 = P[4 * q + 3];
            if (q & 1) {
                Axy1 = __builtin_elementwise_fma((v2f){w0, w0}, (v2f){P0.x, P0.y}, Axy1);
                Azw1 = __builtin_elementwise_fma((v2f){w0, w0}, (v2f){P0.z, P0.w}, Azw1);
                Axy1 = __builtin_elementwise_fma((v2f){w1, w1}, (v2f){P1.x, P1.y}, Axy1);
                Azw1 = __builtin_elementwise_fma((v2f){w1, w1}, (v2f){P1.z, P1.w}, Azw1);
                Axy1 = __builtin_elementwise_fma((v2f){w2, w2}, (v2f){P2.x, P2.y}, Axy1);
                Azw1 = __builtin_elementwise_fma((v2f){w2, w2}, (v2f){P2.z, P2.w}, Azw1);
                Axy1 = __builtin_elementwise_fma((v2f){w3, w3}, (v2f){P3.x, P3.y}, Axy1);
                Azw1 = __builtin_elementwise_fma((v2f){w3, w3}, (v2f){P3.z, P3.w}, Azw1);
            } else {
                Axy0 = __builtin_elementwise_fma((v2f){w0, w0}, (v2f){P0.x, P0.y}, Axy0);
                Azw0 = __builtin_elementwise_fma((v2f){w0, w0}, (v2f){P0.z, P0.w}, Azw0);
                Axy0 = __builtin_elementwise_fma((v2f){w1, w1}, (v2f){P1.x, P1.y}, Axy0);
                Azw0 = __builtin_elementwise_fma((v2f){w1, w1}, (v2f){P1.z, P1.w}, Azw0);
                Axy0 = __builtin_elementwise_fma((v2f){w2, w2}, (v2f){P2.x, P2.y}, Axy0);
                Azw0 = __builtin_elementwise_fma((v2f){w2, w2}, (v2f){P2.z, P2.w}, Azw0);
                Axy0 = __builtin_elementwise_fma((v2f){w3, w3}, (v2f){P3.x, P3.y}, Axy0);
                Azw0 = __builtin_elementwise_fma((v2f){w3, w3}, (v2f){P3.z, P3.w}, Azw0);
            }
        }
    }

    v2f Axy = Axy0 + Axy1;
    v2f Azw = Azw0 + Azw1;

    // halves hold disjoint m-sets for the same n: combine h1 into h0.
    float hx = __shfl(Axy[0], col + 32);
    float hy = __shfl(Axy[1], col + 32);
    float hz = __shfl(Azw[0], col + 32);
    float hd = __shfl(Azw[1], col + 32);
    if (l < 32) {
        float* dst = (float*)&accOut[b * NPTS + n];
        atomicAdd(dst + 0, Axy[0] + hx);
        atomicAdd(dst + 1, Axy[1] + hy);
        atomicAdd(dst + 2, Azw[0] + hz);
        atomicAdd(dst + 3, Azw[1] + hd);
    }
}

__global__ __launch_bounds__(256) void ms_pack(const float4* __restrict__ acc4,
                                               float* __restrict__ out,
                                               float invs) {
    int gid = blockIdx.x * 256 + threadIdx.x;
    int b = gid / NPTS;
    int n = gid - b * NPTS;
    float4 a = acc4[gid];
    float f = invs / a.w;                   // unscale + normalize
    float* ob = out + b * 3 * NPTS;
    ob[n]            = a.x * f;
    ob[NPTS + n]     = a.y * f;
    ob[2 * NPTS + n] = a.z * f;
}

extern "C" void kernel_launch(void* const* d_in, const int* in_sizes, int n_in,
                              void* d_out, int out_size, void* d_ws, size_t ws_size,
                              hipStream_t stream) {
    const float* x = (const float*)d_in[0];
    float* out = (float*)d_out;
    float s = sqrtf(50.0f * LOG2E);

    float4* acc   = (float4*)d_ws;                      // 5*TOT*16B = 1.47MB
    short*  pfeat = (short*)(acc + (size_t)5 * TOT);    // TOT*16*2B = 590KB
    float4* pts4  = (float4*)(pfeat + (size_t)TOT * 16);// TOT*16B = 295KB

    hipMemsetAsync(acc, 0, (size_t)5 * TOT * sizeof(float4), stream);
    ms_feat<<<TOT / 256, 256, 0, stream>>>(x, pfeat, pts4, s);

    for (int it = 0; it < 5; ++it) {
        const float4* accIn = (it == 0) ? nullptr : acc + (size_t)(it - 1) * TOT;
        ms_iter<<<NB * NTIL * MSPL, 256, 0, stream>>>(
            x, accIn, acc + (size_t)it * TOT, pfeat, pts4, s, it == 0 ? 1 : 0);
    }
    ms_pack<<<TOT / 256, 256, 0, stream>>>(acc + (size_t)4 * TOT, out, 1.0f / s);
}